// Round 5
// baseline (597.586 us; speedup 1.0000x reference)
//
#include <hip/hip_runtime.h>

#define N_ATOMS   100000
#define N_BONDS   220000
#define N_MESS    20000
#define N_MSG     (N_MESS + N_BONDS)        // 240000
#define ATOM_FDIM 35
#define BOND_FDIM 5
#define BOND_IN   (ATOM_FDIM + BOND_FDIM)   // 40
#define H         128
#define MAX_NB    10
#define NB_PAD    12                        // padded stride for 16B-aligned idx loads
#define DEPTH     6
#define KO        (ATOM_FDIM + H)           // 163
#define KC        192                       // padded K for both GEMMs
#define QLDS_STR  144                       // byte-stage stride (16-mult, breaks bank alias)

typedef __attribute__((ext_vector_type(8))) short short8;   // 8 bf16 (4 VGPRs)
typedef __attribute__((ext_vector_type(4))) float f32x4;    // MFMA C/D frag

static __device__ __forceinline__ unsigned short f2bf(float f) {
    union { float f; unsigned int i; } v; v.f = f;
    unsigned int x = v.i;
    return (unsigned short)((x + 0x7FFFu + ((x >> 16) & 1u)) >> 16);
}

// byte b of u32 -> float; clang folds to v_cvt_f32_ubyte{0..3}
static __device__ __forceinline__ float ub2f(unsigned int v, int b) {
    return (float)((v >> (b * 8)) & 0xffu);
}

static __device__ __forceinline__ unsigned int q8c(float x) {
    int q = __float2int_rn(x);
    q = q < 0 ? 0 : (q > 255 ? 255 : q);
    return (unsigned int)q;
}

// ---------------------------------------------------------------------------
// prep: fbonds->bf16, weight transposes, graph padding 10->12, out zeroing.
// ---------------------------------------------------------------------------
#define PTa (N_BONDS * BOND_IN)             // fbc
#define PTb (PTa + H * KC)                  // WT
#define PTc (PTb + H * KC)                  // WoT
#define PTd (PTc + N_BONDS * MAX_NB)        // bgraphP
#define PTe (PTd + N_ATOMS * MAX_NB)        // agraphP

__global__ __launch_bounds__(256) void prep(
    const float* __restrict__ fbonds,
    const float* __restrict__ Wi, const float* __restrict__ Wh,
    const float* __restrict__ Wo,
    const int* __restrict__ bgraph, const int* __restrict__ agraph,
    ushort* __restrict__ fbc, ushort* __restrict__ WT,
    ushort* __restrict__ WoT,
    int* __restrict__ bgP, int* __restrict__ agP,
    float* __restrict__ out, int n_out)
{
    int i = blockIdx.x * 256 + threadIdx.x;
    if (i < PTa) {
        fbc[i] = f2bf(fbonds[i]);
    } else if (i < PTb) {
        int j = i - PTa;
        int n = j / KC, k = j - n * KC;
        float v = (k < BOND_IN) ? Wi[k * H + n]
                : (k < BOND_IN + H) ? Wh[(k - BOND_IN) * H + n] : 0.f;
        WT[j] = f2bf(v);
    } else if (i < PTc) {
        int j = i - PTb;
        int n = j / KC, k = j - n * KC;
        float v = (k < H) ? Wo[(ATOM_FDIM + k) * H + n]
                : (k < KO) ? Wo[(k - H) * H + n] : 0.f;
        WoT[j] = f2bf(v);
    } else if (i < PTd) {
        int j = i - PTc;
        int b = j / MAX_NB, n = j - b * MAX_NB;
        bgP[b * NB_PAD + n] = bgraph[j];
    } else if (i < PTe) {
        int j = i - PTd;
        int a = j / MAX_NB, n = j - a * MAX_NB;
        agP[a * NB_PAD + n] = agraph[j];
    } else {
        int j = i - PTe;
        if (j < n_out) out[j] = 0.f;
    }
}

// ---------------------------------------------------------------------------
// qtree: tree rows -> affine u8 (val = sc*u + mn), scale tables (sc, mn).
// One row per wave; constant rows (incl. zero row 0) encode exactly.
// ---------------------------------------------------------------------------
__global__ __launch_bounds__(256) void qtree(
    const float* __restrict__ tree,
    ushort* __restrict__ qA, ushort* __restrict__ qB,
    float2* __restrict__ sA, float2* __restrict__ sB)
{
    int row = blockIdx.x * 4 + (threadIdx.x >> 6);
    int lane = threadIdx.x & 63;
    float2 v = *(const float2*)&tree[(size_t)row * H + lane * 2];
    float mx = fmaxf(v.x, v.y), mn = fminf(v.x, v.y);
    #pragma unroll
    for (int d = 1; d <= 32; d <<= 1) {
        mx = fmaxf(mx, __shfl_xor(mx, d));
        mn = fminf(mn, __shfl_xor(mn, d));
    }
    float rng = mx - mn;
    float inv = (rng > 0.f) ? 255.f / rng : 0.f;
    unsigned q0 = q8c((v.x - mn) * inv);
    unsigned q1 = q8c((v.y - mn) * inv);
    unsigned short pk = (unsigned short)(q0 | (q1 << 8));
    qA[(size_t)row * 64 + lane] = pk;
    qB[(size_t)row * 64 + lane] = pk;
    if (lane == 0) {
        float2 s = make_float2(rng * (1.f / 255.f), mn);
        sA[row] = s; sB[row] = s;
    }
}

// ---------------------------------------------------------------------------
// gather_u8: sum 10 affine-u8 rows (128 B = 1 line each). Scale table is
// L2-resident (1.9 MB) -> scale loads are L2 hits, off the random-line budget.
// Decode = v_cvt_f32_ubyte + v_fmac (2 VALU/value). bf16 pack via HW cvt_pk.
// ---------------------------------------------------------------------------
static __device__ __forceinline__ uint4 gather_u8(
    const uint2* __restrict__ msgq, const float2* __restrict__ scl,
    const int* __restrict__ gidx, int c16)
{
    uint4 i0 = *(const uint4*)gidx;
    uint4 i1 = *(const uint4*)(gidx + 4);
    uint2 i2 = *(const uint2*)(gidx + 8);
    int idx[MAX_NB] = {(int)i0.x, (int)i0.y, (int)i0.z, (int)i0.w,
                       (int)i1.x, (int)i1.y, (int)i1.z, (int)i1.w,
                       (int)i2.x, (int)i2.y};
    float2 so[MAX_NB];
    uint2 d[MAX_NB];
    #pragma unroll
    for (int n = 0; n < MAX_NB; n++) {
        so[n] = scl[idx[n]];
        d[n] = msgq[(size_t)idx[n] * 16 + c16];
    }
    float s0=0.f,s1=0.f,s2=0.f,s3=0.f,s4=0.f,s5=0.f,s6=0.f,s7=0.f;
    float off = 0.f;
    #pragma unroll
    for (int n = 0; n < MAX_NB; n++) {
        float sc = so[n].x; off += so[n].y;
        s0 += sc * ub2f(d[n].x, 0); s1 += sc * ub2f(d[n].x, 1);
        s2 += sc * ub2f(d[n].x, 2); s3 += sc * ub2f(d[n].x, 3);
        s4 += sc * ub2f(d[n].y, 0); s5 += sc * ub2f(d[n].y, 1);
        s6 += sc * ub2f(d[n].y, 2); s7 += sc * ub2f(d[n].y, 3);
    }
    s0 += off; s1 += off; s2 += off; s3 += off;
    s4 += off; s5 += off; s6 += off; s7 += off;
    uint4 pk;
    asm("v_cvt_pk_bf16_f32 %0, %1, %2" : "=v"(pk.x) : "v"(s0), "v"(s1));
    asm("v_cvt_pk_bf16_f32 %0, %1, %2" : "=v"(pk.y) : "v"(s2), "v"(s3));
    asm("v_cvt_pk_bf16_f32 %0, %1, %2" : "=v"(pk.z) : "v"(s4), "v"(s5));
    asm("v_cvt_pk_bf16_f32 %0, %1, %2" : "=v"(pk.w) : "v"(s6), "v"(s7));
    return pk;
}

// ---------------------------------------------------------------------------
// u8_epilogue: relu + per-row u8 quantize (off=0 post-relu). Row max via
// in-wave shfl (16-lane groups) + small LDS fold; bytes staged in LDS
// (stride 144), then uint4 copy-out + scale-table write.
// ---------------------------------------------------------------------------
static __device__ __forceinline__ void u8_epilogue(
    f32x4 c00, f32x4 c01, f32x4 c10, f32x4 c11,
    int tid, int row_base,
    float* rmx /*32*4*/, float* qp /*32*/, char* qlds,
    uint4* __restrict__ gq4, float2* __restrict__ scout)
{
    int lane = tid & 63, wv = tid >> 6;
    int m_lane = lane & 15, quad = lane >> 4;
    int n0 = wv * 32;

    float v00[4], v01[4], v10[4], v11[4];
    #pragma unroll
    for (int r = 0; r < 4; r++) {
        v00[r] = fmaxf(c00[r], 0.f); v01[r] = fmaxf(c01[r], 0.f);
        v10[r] = fmaxf(c10[r], 0.f); v11[r] = fmaxf(c11[r], 0.f);
    }
    #pragma unroll
    for (int r = 0; r < 4; r++) {
        float mx0 = fmaxf(v00[r], v01[r]);
        float mx1 = fmaxf(v10[r], v11[r]);
        #pragma unroll
        for (int d = 1; d <= 8; d <<= 1) {
            mx0 = fmaxf(mx0, __shfl_xor(mx0, d));
            mx1 = fmaxf(mx1, __shfl_xor(mx1, d));
        }
        if (m_lane == 0) {
            rmx[(quad * 4 + r) * 4 + wv]      = mx0;
            rmx[(quad * 4 + r + 16) * 4 + wv] = mx1;
        }
    }
    __syncthreads();
    if (tid < 32) {
        float mx = fmaxf(fmaxf(rmx[tid * 4], rmx[tid * 4 + 1]),
                         fmaxf(rmx[tid * 4 + 2], rmx[tid * 4 + 3]));
        qp[tid] = (mx > 0.f) ? 255.f / mx : 0.f;
        scout[row_base + tid] = make_float2(mx * (1.f / 255.f), 0.f);
    }
    __syncthreads();
    #pragma unroll
    for (int r = 0; r < 4; r++) {
        int r0 = quad * 4 + r, r1 = r0 + 16;
        float i0 = qp[r0], i1 = qp[r1];
        qlds[r0 * QLDS_STR + n0 + m_lane]      = (char)q8c(v00[r] * i0);
        qlds[r0 * QLDS_STR + n0 + 16 + m_lane] = (char)q8c(v01[r] * i0);
        qlds[r1 * QLDS_STR + n0 + m_lane]      = (char)q8c(v10[r] * i1);
        qlds[r1 * QLDS_STR + n0 + 16 + m_lane] = (char)q8c(v11[r] * i1);
    }
    __syncthreads();
    int row = tid >> 3, seg = tid & 7;        // 32 rows x 8 uint4
    uint4 w = *(const uint4*)(qlds + row * QLDS_STR + seg * 16);
    gq4[(size_t)(row_base + row) * 8 + seg] = w;
}

// ---------------------------------------------------------------------------
// binput0 (MFMA): graph0 = relu(fbonds @ W_i) -> u8 rows. K cut to 64.
// ---------------------------------------------------------------------------
__global__ __launch_bounds__(256, 4) void binput0(
    const ushort* __restrict__ fbc, const ushort* __restrict__ WT,
    uint4* __restrict__ gq_out, float2* __restrict__ sc_out)
{
    __shared__ ushort Xlds[32 * 25 * 8];
    __shared__ __align__(16) char qlds[32 * QLDS_STR];
    __shared__ float rmx[32 * 4];
    __shared__ float qp[32];

    int tid = threadIdx.x;
    int bond0 = blockIdx.x * 32;           // grid = 6875, exact
    int lane = tid & 63, wv = tid >> 6;

    if (tid < 160) {                       // b = tid/5, k8 = tid%5
        int b = tid / 5, k8 = tid - b * 5;
        *(short8*)&Xlds[(b * 25 + k8) * 8] =
            *(const short8*)&fbc[(size_t)bond0 * BOND_IN + tid * 8];
    }
    if (tid < 96) {                        // zero k in [40,64): cells 5..7
        int b = tid / 3, k8 = 5 + (tid - b * 3);
        *(float4*)&Xlds[(b * 25 + k8) * 8] = float4{0.f, 0.f, 0.f, 0.f};
    }
    __syncthreads();

    int n0 = wv * 32;
    int m_lane = lane & 15, quad = lane >> 4;
    f32x4 c00 = {0,0,0,0}, c01 = {0,0,0,0}, c10 = {0,0,0,0}, c11 = {0,0,0,0};

    #pragma unroll
    for (int s = 0; s < 2; s++) {          // K = 64 covers fb (k<40) + zeros
        short8 a0 = *(const short8*)&Xlds[((m_lane)      * 25 + s * 4 + quad) * 8];
        short8 a1 = *(const short8*)&Xlds[((16 + m_lane) * 25 + s * 4 + quad) * 8];
        short8 b0 = *(const short8*)&WT[(size_t)(n0 + m_lane)      * KC + s * 32 + quad * 8];
        short8 b1 = *(const short8*)&WT[(size_t)(n0 + 16 + m_lane) * KC + s * 32 + quad * 8];
        c00 = __builtin_amdgcn_mfma_f32_16x16x32_bf16(a0, b0, c00, 0, 0, 0);
        c01 = __builtin_amdgcn_mfma_f32_16x16x32_bf16(a0, b1, c01, 0, 0, 0);
        c10 = __builtin_amdgcn_mfma_f32_16x16x32_bf16(a1, b0, c10, 0, 0, 0);
        c11 = __builtin_amdgcn_mfma_f32_16x16x32_bf16(a1, b1, c11, 0, 0, 0);
    }

    u8_epilogue(c00, c01, c10, c11, tid, bond0, rmx, qp, qlds, gq_out, sc_out);
}

// ---------------------------------------------------------------------------
// mp_round (MFMA): graph_out[b] = relu([fb[b]|nei[b]|0] @ [Wi;Wh;0])
// Gather: u8 rows, 1 random line per neighbor + L2-hit scale loads.
// ---------------------------------------------------------------------------
__global__ __launch_bounds__(256, 4) void mp_round(
    const uint2* __restrict__ msg_in, const float2* __restrict__ sc_in,
    const ushort* __restrict__ fbc, const int* __restrict__ bgraphP,
    const ushort* __restrict__ WT,
    uint4* __restrict__ gq_out, float2* __restrict__ sc_out)
{
    __shared__ ushort Xlds[32 * 25 * 8];   // 800 cells x 16 B = 12800 B
    __shared__ __align__(16) char qlds[32 * QLDS_STR];
    __shared__ float rmx[32 * 4];
    __shared__ float qp[32];

    int tid = threadIdx.x;
    int bond0 = blockIdx.x * 32;           // grid = 6875, exact
    int lane = tid & 63, wv = tid >> 6;
    int q = lane >> 4, c16 = lane & 15;

    // stage fb tile (pre-converted bf16): 160 x 16 B copies
    if (tid < 160) {
        int b = tid / 5, k8 = tid - b * 5;
        *(short8*)&Xlds[(b * 25 + k8) * 8] =
            *(const short8*)&fbc[(size_t)bond0 * BOND_IN + tid * 8];
    }
    // zero pad k in [168,192): cells 21..23
    if (tid < 96) {
        int b = tid / 3, k8 = 21 + (tid - b * 3);
        *(float4*)&Xlds[(b * 25 + k8) * 8] = float4{0.f, 0.f, 0.f, 0.f};
    }
    // gather nei: wave wv covers rows wv+4t, t = g*4+q; lane sums elements
    // [c16*8, c16*8+8) of its row -> cell 5+c16.
    #pragma unroll
    for (int g = 0; g < 2; g++) {
        int b = wv + 4 * (g * 4 + q);
        uint4 pk = gather_u8(msg_in, sc_in,
                             bgraphP + (size_t)(bond0 + b) * NB_PAD, c16);
        *(uint4*)&Xlds[(b * 25 + 5 + c16) * 8] = pk;
    }
    __syncthreads();

    int n0 = wv * 32;
    int m_lane = lane & 15, quad = lane >> 4;
    f32x4 c00 = {0,0,0,0}, c01 = {0,0,0,0}, c10 = {0,0,0,0}, c11 = {0,0,0,0};

    #pragma unroll
    for (int s = 0; s < KC / 32; s++) {
        short8 a0 = *(const short8*)&Xlds[((m_lane)      * 25 + s * 4 + quad) * 8];
        short8 a1 = *(const short8*)&Xlds[((16 + m_lane) * 25 + s * 4 + quad) * 8];
        short8 b0 = *(const short8*)&WT[(size_t)(n0 + m_lane)      * KC + s * 32 + quad * 8];
        short8 b1 = *(const short8*)&WT[(size_t)(n0 + 16 + m_lane) * KC + s * 32 + quad * 8];
        c00 = __builtin_amdgcn_mfma_f32_16x16x32_bf16(a0, b0, c00, 0, 0, 0);
        c01 = __builtin_amdgcn_mfma_f32_16x16x32_bf16(a0, b1, c01, 0, 0, 0);
        c10 = __builtin_amdgcn_mfma_f32_16x16x32_bf16(a1, b0, c10, 0, 0, 0);
        c11 = __builtin_amdgcn_mfma_f32_16x16x32_bf16(a1, b1, c11, 0, 0, 0);
    }

    u8_epilogue(c00, c01, c10, c11, tid, bond0, rmx, qp, qlds, gq_out, sc_out);
}

// ---------------------------------------------------------------------------
// atom_mfma: relu([nei|fatoms|0] @ WoT^T + b_o), then per-molecule partial
// sums reduced in LDS and atomicAdd'ed into out. Gather path u8.
// ---------------------------------------------------------------------------
__global__ __launch_bounds__(256, 4) void atom_mfma(
    const float* __restrict__ fatoms, const uint2* __restrict__ msg,
    const float2* __restrict__ scl,
    const int* __restrict__ agraphP, const ushort* __restrict__ WoT,
    const float* __restrict__ bo, const int* __restrict__ mol_ids,
    float* __restrict__ out)
{
    __shared__ ushort Xlds[32 * 25 * 8];
    __shared__ float htile[32 * H];
    __shared__ int mlds[32];

    int tid = threadIdx.x;
    int a0 = blockIdx.x * 32;              // grid = 3125, exact
    int lane = tid & 63, wv = tid >> 6;
    int q = lane >> 4, c16 = lane & 15;

    // fatoms: k in [128,163)
    for (int i = tid; i < 32 * ATOM_FDIM; i += 256) {
        int b = i / ATOM_FDIM, t = i - b * ATOM_FDIM;
        int k = H + t;
        Xlds[(b * 25 + (k >> 3)) * 8 + (k & 7)] = f2bf(fatoms[(size_t)a0 * ATOM_FDIM + i]);
    }
    // zero k in [163,168)
    if (tid < 160) {
        int b = tid / 5, k = 163 + (tid - b * 5);
        Xlds[(b * 25 + (k >> 3)) * 8 + (k & 7)] = 0;
    }
    // zero cells 21..23 (k in [168,192))
    if (tid < 96) {
        int b = tid / 3, k8 = 21 + (tid - b * 3);
        *(float4*)&Xlds[(b * 25 + k8) * 8] = float4{0.f, 0.f, 0.f, 0.f};
    }
    if (tid < 32) mlds[tid] = mol_ids[a0 + tid];
    // gather nei: k in [0,128) -> cell c16
    #pragma unroll
    for (int g = 0; g < 2; g++) {
        int b = wv + 4 * (g * 4 + q);
        uint4 pk = gather_u8(msg, scl,
                             agraphP + (size_t)(a0 + b) * NB_PAD, c16);
        *(uint4*)&Xlds[(b * 25 + c16) * 8] = pk;
    }
    __syncthreads();

    int n0 = wv * 32;
    int m_lane = lane & 15, quad = lane >> 4;
    float bias0 = bo[n0 + m_lane], bias1 = bo[n0 + 16 + m_lane];
    f32x4 c00 = {bias0, bias0, bias0, bias0};
    f32x4 c01 = {bias1, bias1, bias1, bias1};
    f32x4 c10 = {bias0, bias0, bias0, bias0};
    f32x4 c11 = {bias1, bias1, bias1, bias1};

    #pragma unroll
    for (int s = 0; s < KC / 32; s++) {
        short8 a0f = *(const short8*)&Xlds[((m_lane)      * 25 + s * 4 + quad) * 8];
        short8 a1f = *(const short8*)&Xlds[((16 + m_lane) * 25 + s * 4 + quad) * 8];
        short8 b0f = *(const short8*)&WoT[(size_t)(n0 + m_lane)      * KC + s * 32 + quad * 8];
        short8 b1f = *(const short8*)&WoT[(size_t)(n0 + 16 + m_lane) * KC + s * 32 + quad * 8];
        c00 = __builtin_amdgcn_mfma_f32_16x16x32_bf16(a0f, b0f, c00, 0, 0, 0);
        c01 = __builtin_amdgcn_mfma_f32_16x16x32_bf16(a0f, b1f, c01, 0, 0, 0);
        c10 = __builtin_amdgcn_mfma_f32_16x16x32_bf16(a1f, b0f, c10, 0, 0, 0);
        c11 = __builtin_amdgcn_mfma_f32_16x16x32_bf16(a1f, b1f, c11, 0, 0, 0);
    }

    #pragma unroll
    for (int r = 0; r < 4; r++) {
        int r0 = quad * 4 + r, r1 = r0 + 16;
        htile[r0 * H + n0 + m_lane]      = fmaxf(c00[r], 0.f);
        htile[r0 * H + n0 + 16 + m_lane] = fmaxf(c01[r], 0.f);
        htile[r1 * H + n0 + m_lane]      = fmaxf(c10[r], 0.f);
        htile[r1 * H + n0 + 16 + m_lane] = fmaxf(c11[r], 0.f);
    }
    __syncthreads();

    // segmented reduce over the 32-atom tile, one atomicAdd per (segment,col)
    if (tid < H) {
        int j = tid;
        float acc = 0.f;
        int cur = mlds[0];
        for (int r = 0; r < 32; r++) {
            int m = mlds[r];
            if (m != cur) {
                atomicAdd(&out[(size_t)cur * H + j], acc);
                acc = 0.f; cur = m;
            }
            acc += htile[r * H + j];
        }
        atomicAdd(&out[(size_t)cur * H + j], acc);
    }
}

// ---------------------------------------------------------------------------
// pool_div: out[m] /= count(m)  (counts via binary search on sorted mol_ids)
// ---------------------------------------------------------------------------
__global__ __launch_bounds__(128) void pool_div(
    const int* __restrict__ mol_ids, float* __restrict__ out, int n_atoms)
{
    int m = blockIdx.x;
    int j = threadIdx.x;

    int lo = 0, hi = n_atoms;
    while (lo < hi) { int mid = (lo + hi) >> 1; if (mol_ids[mid] < m) lo = mid + 1; else hi = mid; }
    int start = lo;
    hi = n_atoms;
    while (lo < hi) { int mid = (lo + hi) >> 1; if (mol_ids[mid] < m + 1) lo = mid + 1; else hi = mid; }
    int end = lo;

    out[(size_t)m * H + j] /= fmaxf((float)(end - start), 1.f);
}

// ---------------------------------------------------------------------------
extern "C" void kernel_launch(void* const* d_in, const int* in_sizes, int n_in,
                              void* d_out, int out_size, void* d_ws, size_t ws_size,
                              hipStream_t stream)
{
    const float* fatoms  = (const float*)d_in[0];
    const float* fbonds  = (const float*)d_in[1];
    const float* tree    = (const float*)d_in[2];
    const int*   agraph  = (const int*)d_in[3];
    const int*   bgraph  = (const int*)d_in[4];
    const int*   mol_ids = (const int*)d_in[5];
    const float* W_i = (const float*)d_in[7];
    const float* W_h = (const float*)d_in[8];
    const float* W_o = (const float*)d_in[9];
    const float* b_o = (const float*)d_in[10];
    float* out = (float*)d_out;

    // ws: mqA | mqB (u8 rows, 30.72 MB each) | scA | scB (float2, 1.92 MB each)
    //     | WT | WoT (48 KB each) | fbc (17.6 MB) | bgraphP (10.56 MB)
    //     | agraphP (4.8 MB)   ~98 MB
    uint2* mqA = (uint2*)d_ws;
    uint2* mqB = mqA + (size_t)N_MSG * 16;
    float2* scA = (float2*)(mqB + (size_t)N_MSG * 16);
    float2* scB = scA + N_MSG;
    ushort* WT  = (ushort*)(scB + N_MSG);
    ushort* WoT = WT + (size_t)H * KC;
    ushort* fbc = WoT + (size_t)H * KC;
    int* bgP = (int*)(fbc + (size_t)N_BONDS * BOND_IN);
    int* agP = bgP + (size_t)N_BONDS * NB_PAD;

    int prep_total = PTe + out_size;
    prep<<<(prep_total + 255) / 256, 256, 0, stream>>>(
        fbonds, W_i, W_h, W_o, bgraph, agraph, fbc, WT, WoT, bgP, agP, out, out_size);

    qtree<<<N_MESS / 4, 256, 0, stream>>>(tree, (ushort*)mqA, (ushort*)mqB, scA, scB);

    binput0<<<N_BONDS / 32, 256, 0, stream>>>(fbc, WT,
        (uint4*)(mqA + (size_t)N_MESS * 16), scA + N_MESS);

    const uint2* tin = mqA; const float2* sin = scA;
    uint2* tout = mqB; float2* sout = scB;
    for (int r = 0; r < DEPTH - 1; r++) {
        mp_round<<<N_BONDS / 32, 256, 0, stream>>>(tin, sin, fbc, bgP, WT,
            (uint4*)(tout + (size_t)N_MESS * 16), sout + N_MESS);
        const uint2* t1 = tin; tin = tout; tout = (uint2*)t1;
        const float2* t2 = sin; sin = sout; sout = (float2*)t2;
    }
    // after 5 rounds the final message table is mqB (== tin)

    atom_mfma<<<N_ATOMS / 32, 256, 0, stream>>>(fatoms, tin, sin, agP, WoT, b_o,
                                                mol_ids, out);

    int n_mols = out_size / H;
    pool_div<<<n_mols, 128, 0, stream>>>(mol_ids, out, N_ATOMS);
}

// Round 6
// 546.019 us; speedup vs baseline: 1.0944x; 1.0944x over previous
//
#include <hip/hip_runtime.h>

#define N_ATOMS   100000
#define N_BONDS   220000
#define N_MESS    20000
#define N_MSG     (N_MESS + N_BONDS)        // 240000
#define ATOM_FDIM 35
#define BOND_FDIM 5
#define BOND_IN   (ATOM_FDIM + BOND_FDIM)   // 40
#define H         128
#define MAX_NB    10
#define NB_PAD    12                        // padded stride for 16B-aligned idx loads
#define DEPTH     6
#define KO        (ATOM_FDIM + H)           // 163
#define KC        192                       // padded K for both GEMMs
#define QLDS_STR  144                       // byte-stage stride (16-mult, breaks bank alias)
#define SC_BIAS   887u                      // scf = asf((code+887)<<20), 3 mantissa bits

typedef __attribute__((ext_vector_type(8))) short short8;   // 8 bf16 (4 VGPRs)
typedef __attribute__((ext_vector_type(4))) float f32x4;    // MFMA C/D frag

static __device__ __forceinline__ float asf(unsigned int u) {
    union { unsigned int i; float f; } v; v.i = u; return v.f;
}

static __device__ __forceinline__ unsigned short f2bf(float f) {
    union { float f; unsigned int i; } v; v.f = f;
    unsigned int x = v.i;
    return (unsigned short)((x + 0x7FFFu + ((x >> 16) & 1u)) >> 16);
}

// byte b of u32 -> float; clang folds to v_cvt_f32_ubyte{0..3}
static __device__ __forceinline__ float ub2f(unsigned int v, int b) {
    return (float)((v >> (b * 8)) & 0xffu);
}

// scale code from row max-abs: smallest code with scf >= mx/127 (round UP)
static __device__ __forceinline__ int sc_code(float mx) {
    float t = mx * (1.f / 127.f);
    int code = (int)((__float_as_uint(t) + 0xFFFFFu) >> 20) - (int)SC_BIAS;
    return code < 1 ? 1 : (code > 255 ? 255 : code);
}
static __device__ __forceinline__ float sc_val(int code) {
    return asf(((unsigned)code + SC_BIAS) << 20);
}

// ---------------------------------------------------------------------------
// prep: fbonds->bf16, weight transposes, graph padding 10->12, out zeroing.
// ---------------------------------------------------------------------------
#define PTa (N_BONDS * BOND_IN)             // fbc
#define PTb (PTa + H * KC)                  // WT
#define PTc (PTb + H * KC)                  // WoT
#define PTd (PTc + N_BONDS * MAX_NB)        // bgraphP
#define PTe (PTd + N_ATOMS * MAX_NB)        // agraphP

__global__ __launch_bounds__(256) void prep(
    const float* __restrict__ fbonds,
    const float* __restrict__ Wi, const float* __restrict__ Wh,
    const float* __restrict__ Wo,
    const int* __restrict__ bgraph, const int* __restrict__ agraph,
    ushort* __restrict__ fbc, ushort* __restrict__ WT,
    ushort* __restrict__ WoT,
    int* __restrict__ bgP, int* __restrict__ agP,
    float* __restrict__ out, int n_out)
{
    int i = blockIdx.x * 256 + threadIdx.x;
    if (i < PTa) {
        fbc[i] = f2bf(fbonds[i]);
    } else if (i < PTb) {
        int j = i - PTa;
        int n = j / KC, k = j - n * KC;
        float v = (k < BOND_IN) ? Wi[k * H + n]
                : (k < BOND_IN + H) ? Wh[(k - BOND_IN) * H + n] : 0.f;
        WT[j] = f2bf(v);
    } else if (i < PTc) {
        int j = i - PTb;
        int n = j / KC, k = j - n * KC;
        float v = (k < H) ? Wo[(ATOM_FDIM + k) * H + n]
                : (k < KO) ? Wo[(k - H) * H + n] : 0.f;
        WoT[j] = f2bf(v);
    } else if (i < PTd) {
        int j = i - PTc;
        int b = j / MAX_NB, n = j - b * MAX_NB;
        bgP[b * NB_PAD + n] = bgraph[j];
    } else if (i < PTe) {
        int j = i - PTd;
        int a = j / MAX_NB, n = j - a * MAX_NB;
        agP[a * NB_PAD + n] = agraph[j];
    } else {
        int j = i - PTe;
        if (j < n_out) out[j] = 0.f;
    }
}

// ---------------------------------------------------------------------------
// qtree: tree rows -> bias-128 u8 (val = scf*(u-128)) + 1-byte scale code.
// One row per wave. Row 0 (zero row): mx=0 -> code=1, u=128 -> decodes to 0.
// ---------------------------------------------------------------------------
__global__ __launch_bounds__(256) void qtree(
    const float* __restrict__ tree,
    ushort* __restrict__ qA, ushort* __restrict__ qB,
    unsigned char* __restrict__ sA, unsigned char* __restrict__ sB)
{
    int row = blockIdx.x * 4 + (threadIdx.x >> 6);
    int lane = threadIdx.x & 63;
    float2 v = *(const float2*)&tree[(size_t)row * H + lane * 2];
    float mx = fmaxf(fabsf(v.x), fabsf(v.y));
    #pragma unroll
    for (int d = 1; d <= 32; d <<= 1)
        mx = fmaxf(mx, __shfl_xor(mx, d));
    int code = sc_code(mx);
    float inv = __builtin_amdgcn_rcpf(sc_val(code));
    int u0 = __float2int_rn(v.x * inv) + 128;
    int u1 = __float2int_rn(v.y * inv) + 128;
    u0 = u0 < 0 ? 0 : (u0 > 255 ? 255 : u0);
    u1 = u1 < 0 ? 0 : (u1 > 255 ? 255 : u1);
    unsigned short pk = (unsigned short)(u0 | (u1 << 8));
    qA[(size_t)row * 64 + lane] = pk;
    qB[(size_t)row * 64 + lane] = pk;
    if (lane == 0) { sA[row] = (unsigned char)code; sB[row] = (unsigned char)code; }
}

// ---------------------------------------------------------------------------
// gather_u8c: sum 10 bias-128 u8 rows (128 B = 1 line each). Scales are
// 1-byte codes in a 240 KB table (L2-hot). Decode = cvt_f32_ubyte + fmac;
// bias removed once at the end via s -= 128*sum(scf).
// ---------------------------------------------------------------------------
static __device__ __forceinline__ uint4 gather_u8c(
    const uint2* __restrict__ msgq, const unsigned char* __restrict__ scl,
    const int* __restrict__ gidx, int c16)
{
    uint4 i0 = *(const uint4*)gidx;
    uint4 i1 = *(const uint4*)(gidx + 4);
    uint2 i2 = *(const uint2*)(gidx + 8);
    int idx[MAX_NB] = {(int)i0.x, (int)i0.y, (int)i0.z, (int)i0.w,
                       (int)i1.x, (int)i1.y, (int)i1.z, (int)i1.w,
                       (int)i2.x, (int)i2.y};
    float scf[MAX_NB];
    uint2 d[MAX_NB];
    #pragma unroll
    for (int n = 0; n < MAX_NB; n++) {
        scf[n] = sc_val((int)scl[idx[n]]);
        d[n] = msgq[(size_t)idx[n] * 16 + c16];
    }
    float s0=0.f,s1=0.f,s2=0.f,s3=0.f,s4=0.f,s5=0.f,s6=0.f,s7=0.f;
    float ssum = 0.f;
    #pragma unroll
    for (int n = 0; n < MAX_NB; n++) {
        float sc = scf[n]; ssum += sc;
        s0 += sc * ub2f(d[n].x, 0); s1 += sc * ub2f(d[n].x, 1);
        s2 += sc * ub2f(d[n].x, 2); s3 += sc * ub2f(d[n].x, 3);
        s4 += sc * ub2f(d[n].y, 0); s5 += sc * ub2f(d[n].y, 1);
        s6 += sc * ub2f(d[n].y, 2); s7 += sc * ub2f(d[n].y, 3);
    }
    s0 = fmaf(-128.f, ssum, s0); s1 = fmaf(-128.f, ssum, s1);
    s2 = fmaf(-128.f, ssum, s2); s3 = fmaf(-128.f, ssum, s3);
    s4 = fmaf(-128.f, ssum, s4); s5 = fmaf(-128.f, ssum, s5);
    s6 = fmaf(-128.f, ssum, s6); s7 = fmaf(-128.f, ssum, s7);
    uint4 pk;
    asm("v_cvt_pk_bf16_f32 %0, %1, %2" : "=v"(pk.x) : "v"(s0), "v"(s1));
    asm("v_cvt_pk_bf16_f32 %0, %1, %2" : "=v"(pk.y) : "v"(s2), "v"(s3));
    asm("v_cvt_pk_bf16_f32 %0, %1, %2" : "=v"(pk.z) : "v"(s4), "v"(s5));
    asm("v_cvt_pk_bf16_f32 %0, %1, %2" : "=v"(pk.w) : "v"(s6), "v"(s7));
    return pk;
}

// ---------------------------------------------------------------------------
// u8_epilogue: relu + per-row bias-128 u8 quantize with 1-byte scale code.
// Row max via shfl (16-lane groups) + LDS fold; bytes staged in LDS
// (stride 144), then uint4 copy-out + code byte write.
// ---------------------------------------------------------------------------
static __device__ __forceinline__ void u8_epilogue(
    f32x4 c00, f32x4 c01, f32x4 c10, f32x4 c11,
    int tid, int row_base,
    float* rmx /*32*4*/, float* qp /*32*/, char* qlds,
    uint4* __restrict__ gq4, unsigned char* __restrict__ scout)
{
    int lane = tid & 63, wv = tid >> 6;
    int m_lane = lane & 15, quad = lane >> 4;
    int n0 = wv * 32;

    float v00[4], v01[4], v10[4], v11[4];
    #pragma unroll
    for (int r = 0; r < 4; r++) {
        v00[r] = fmaxf(c00[r], 0.f); v01[r] = fmaxf(c01[r], 0.f);
        v10[r] = fmaxf(c10[r], 0.f); v11[r] = fmaxf(c11[r], 0.f);
    }
    #pragma unroll
    for (int r = 0; r < 4; r++) {
        float mx0 = fmaxf(v00[r], v01[r]);
        float mx1 = fmaxf(v10[r], v11[r]);
        #pragma unroll
        for (int d = 1; d <= 8; d <<= 1) {
            mx0 = fmaxf(mx0, __shfl_xor(mx0, d));
            mx1 = fmaxf(mx1, __shfl_xor(mx1, d));
        }
        if (m_lane == 0) {
            rmx[(quad * 4 + r) * 4 + wv]      = mx0;
            rmx[(quad * 4 + r + 16) * 4 + wv] = mx1;
        }
    }
    __syncthreads();
    if (tid < 32) {
        float mx = fmaxf(fmaxf(rmx[tid * 4], rmx[tid * 4 + 1]),
                         fmaxf(rmx[tid * 4 + 2], rmx[tid * 4 + 3]));
        int code = sc_code(mx);
        qp[tid] = __builtin_amdgcn_rcpf(sc_val(code));
        scout[row_base + tid] = (unsigned char)code;
    }
    __syncthreads();
    #pragma unroll
    for (int r = 0; r < 4; r++) {
        int r0 = quad * 4 + r, r1 = r0 + 16;
        float i0 = qp[r0], i1 = qp[r1];
        // post-relu x >= 0 -> u in [128,255]; clamp top only
        int u00 = __float2int_rn(v00[r] * i0) + 128;
        int u01 = __float2int_rn(v01[r] * i0) + 128;
        int u10 = __float2int_rn(v10[r] * i1) + 128;
        int u11 = __float2int_rn(v11[r] * i1) + 128;
        qlds[r0 * QLDS_STR + n0 + m_lane]      = (char)(u00 > 255 ? 255 : u00);
        qlds[r0 * QLDS_STR + n0 + 16 + m_lane] = (char)(u01 > 255 ? 255 : u01);
        qlds[r1 * QLDS_STR + n0 + m_lane]      = (char)(u10 > 255 ? 255 : u10);
        qlds[r1 * QLDS_STR + n0 + 16 + m_lane] = (char)(u11 > 255 ? 255 : u11);
    }
    __syncthreads();
    int row = tid >> 3, seg = tid & 7;        // 32 rows x 8 uint4
    uint4 w = *(const uint4*)(qlds + row * QLDS_STR + seg * 16);
    gq4[(size_t)(row_base + row) * 8 + seg] = w;
}

// ---------------------------------------------------------------------------
// binput0 (MFMA): graph0 = relu(fbonds @ W_i) -> u8 rows. K cut to 64.
// ---------------------------------------------------------------------------
__global__ __launch_bounds__(256, 4) void binput0(
    const ushort* __restrict__ fbc, const ushort* __restrict__ WT,
    uint4* __restrict__ gq_out, unsigned char* __restrict__ sc_out)
{
    __shared__ ushort Xlds[32 * 25 * 8];
    __shared__ __align__(16) char qlds[32 * QLDS_STR];
    __shared__ float rmx[32 * 4];
    __shared__ float qp[32];

    int tid = threadIdx.x;
    int bond0 = blockIdx.x * 32;           // grid = 6875, exact
    int lane = tid & 63, wv = tid >> 6;

    if (tid < 160) {                       // b = tid/5, k8 = tid%5
        int b = tid / 5, k8 = tid - b * 5;
        *(short8*)&Xlds[(b * 25 + k8) * 8] =
            *(const short8*)&fbc[(size_t)bond0 * BOND_IN + tid * 8];
    }
    if (tid < 96) {                        // zero k in [40,64): cells 5..7
        int b = tid / 3, k8 = 5 + (tid - b * 3);
        *(float4*)&Xlds[(b * 25 + k8) * 8] = float4{0.f, 0.f, 0.f, 0.f};
    }
    __syncthreads();

    int n0 = wv * 32;
    int m_lane = lane & 15, quad = lane >> 4;
    f32x4 c00 = {0,0,0,0}, c01 = {0,0,0,0}, c10 = {0,0,0,0}, c11 = {0,0,0,0};

    #pragma unroll
    for (int s = 0; s < 2; s++) {          // K = 64 covers fb (k<40) + zeros
        short8 a0 = *(const short8*)&Xlds[((m_lane)      * 25 + s * 4 + quad) * 8];
        short8 a1 = *(const short8*)&Xlds[((16 + m_lane) * 25 + s * 4 + quad) * 8];
        short8 b0 = *(const short8*)&WT[(size_t)(n0 + m_lane)      * KC + s * 32 + quad * 8];
        short8 b1 = *(const short8*)&WT[(size_t)(n0 + 16 + m_lane) * KC + s * 32 + quad * 8];
        c00 = __builtin_amdgcn_mfma_f32_16x16x32_bf16(a0, b0, c00, 0, 0, 0);
        c01 = __builtin_amdgcn_mfma_f32_16x16x32_bf16(a0, b1, c01, 0, 0, 0);
        c10 = __builtin_amdgcn_mfma_f32_16x16x32_bf16(a1, b0, c10, 0, 0, 0);
        c11 = __builtin_amdgcn_mfma_f32_16x16x32_bf16(a1, b1, c11, 0, 0, 0);
    }

    u8_epilogue(c00, c01, c10, c11, tid, bond0, rmx, qp, qlds, gq_out, sc_out);
}

// ---------------------------------------------------------------------------
// mp_round (MFMA): graph_out[b] = relu([fb[b]|nei[b]|0] @ [Wi;Wh;0])
// Gather: u8 rows (1 random line each) + 1-byte code loads (240 KB hot set).
// ---------------------------------------------------------------------------
__global__ __launch_bounds__(256, 4) void mp_round(
    const uint2* __restrict__ msg_in, const unsigned char* __restrict__ sc_in,
    const ushort* __restrict__ fbc, const int* __restrict__ bgraphP,
    const ushort* __restrict__ WT,
    uint4* __restrict__ gq_out, unsigned char* __restrict__ sc_out)
{
    __shared__ ushort Xlds[32 * 25 * 8];   // 800 cells x 16 B = 12800 B
    __shared__ __align__(16) char qlds[32 * QLDS_STR];
    __shared__ float rmx[32 * 4];
    __shared__ float qp[32];

    int tid = threadIdx.x;
    int bond0 = blockIdx.x * 32;           // grid = 6875, exact
    int lane = tid & 63, wv = tid >> 6;
    int q = lane >> 4, c16 = lane & 15;

    // stage fb tile (pre-converted bf16): 160 x 16 B copies
    if (tid < 160) {
        int b = tid / 5, k8 = tid - b * 5;
        *(short8*)&Xlds[(b * 25 + k8) * 8] =
            *(const short8*)&fbc[(size_t)bond0 * BOND_IN + tid * 8];
    }
    // zero pad k in [168,192): cells 21..23
    if (tid < 96) {
        int b = tid / 3, k8 = 21 + (tid - b * 3);
        *(float4*)&Xlds[(b * 25 + k8) * 8] = float4{0.f, 0.f, 0.f, 0.f};
    }
    // gather nei: wave wv covers rows wv+4t, t = g*4+q; lane sums elements
    // [c16*8, c16*8+8) of its row -> cell 5+c16.
    #pragma unroll
    for (int g = 0; g < 2; g++) {
        int b = wv + 4 * (g * 4 + q);
        uint4 pk = gather_u8c(msg_in, sc_in,
                              bgraphP + (size_t)(bond0 + b) * NB_PAD, c16);
        *(uint4*)&Xlds[(b * 25 + 5 + c16) * 8] = pk;
    }
    __syncthreads();

    int n0 = wv * 32;
    int m_lane = lane & 15, quad = lane >> 4;
    f32x4 c00 = {0,0,0,0}, c01 = {0,0,0,0}, c10 = {0,0,0,0}, c11 = {0,0,0,0};

    #pragma unroll
    for (int s = 0; s < KC / 32; s++) {
        short8 a0 = *(const short8*)&Xlds[((m_lane)      * 25 + s * 4 + quad) * 8];
        short8 a1 = *(const short8*)&Xlds[((16 + m_lane) * 25 + s * 4 + quad) * 8];
        short8 b0 = *(const short8*)&WT[(size_t)(n0 + m_lane)      * KC + s * 32 + quad * 8];
        short8 b1 = *(const short8*)&WT[(size_t)(n0 + 16 + m_lane) * KC + s * 32 + quad * 8];
        c00 = __builtin_amdgcn_mfma_f32_16x16x32_bf16(a0, b0, c00, 0, 0, 0);
        c01 = __builtin_amdgcn_mfma_f32_16x16x32_bf16(a0, b1, c01, 0, 0, 0);
        c10 = __builtin_amdgcn_mfma_f32_16x16x32_bf16(a1, b0, c10, 0, 0, 0);
        c11 = __builtin_amdgcn_mfma_f32_16x16x32_bf16(a1, b1, c11, 0, 0, 0);
    }

    u8_epilogue(c00, c01, c10, c11, tid, bond0, rmx, qp, qlds, gq_out, sc_out);
}

// ---------------------------------------------------------------------------
// atom_mfma: relu([nei|fatoms|0] @ WoT^T + b_o), then per-molecule partial
// sums reduced in LDS and atomicAdd'ed into out. Gather path u8+code.
// ---------------------------------------------------------------------------
__global__ __launch_bounds__(256, 4) void atom_mfma(
    const float* __restrict__ fatoms, const uint2* __restrict__ msg,
    const unsigned char* __restrict__ scl,
    const int* __restrict__ agraphP, const ushort* __restrict__ WoT,
    const float* __restrict__ bo, const int* __restrict__ mol_ids,
    float* __restrict__ out)
{
    __shared__ ushort Xlds[32 * 25 * 8];
    __shared__ float htile[32 * H];
    __shared__ int mlds[32];

    int tid = threadIdx.x;
    int a0 = blockIdx.x * 32;              // grid = 3125, exact
    int lane = tid & 63, wv = tid >> 6;
    int q = lane >> 4, c16 = lane & 15;

    // fatoms: k in [128,163)
    for (int i = tid; i < 32 * ATOM_FDIM; i += 256) {
        int b = i / ATOM_FDIM, t = i - b * ATOM_FDIM;
        int k = H + t;
        Xlds[(b * 25 + (k >> 3)) * 8 + (k & 7)] = f2bf(fatoms[(size_t)a0 * ATOM_FDIM + i]);
    }
    // zero k in [163,168)
    if (tid < 160) {
        int b = tid / 5, k = 163 + (tid - b * 5);
        Xlds[(b * 25 + (k >> 3)) * 8 + (k & 7)] = 0;
    }
    // zero cells 21..23 (k in [168,192))
    if (tid < 96) {
        int b = tid / 3, k8 = 21 + (tid - b * 3);
        *(float4*)&Xlds[(b * 25 + k8) * 8] = float4{0.f, 0.f, 0.f, 0.f};
    }
    if (tid < 32) mlds[tid] = mol_ids[a0 + tid];
    // gather nei: k in [0,128) -> cell c16
    #pragma unroll
    for (int g = 0; g < 2; g++) {
        int b = wv + 4 * (g * 4 + q);
        uint4 pk = gather_u8c(msg, scl,
                              agraphP + (size_t)(a0 + b) * NB_PAD, c16);
        *(uint4*)&Xlds[(b * 25 + c16) * 8] = pk;
    }
    __syncthreads();

    int n0 = wv * 32;
    int m_lane = lane & 15, quad = lane >> 4;
    float bias0 = bo[n0 + m_lane], bias1 = bo[n0 + 16 + m_lane];
    f32x4 c00 = {bias0, bias0, bias0, bias0};
    f32x4 c01 = {bias1, bias1, bias1, bias1};
    f32x4 c10 = {bias0, bias0, bias0, bias0};
    f32x4 c11 = {bias1, bias1, bias1, bias1};

    #pragma unroll
    for (int s = 0; s < KC / 32; s++) {
        short8 a0f = *(const short8*)&Xlds[((m_lane)      * 25 + s * 4 + quad) * 8];
        short8 a1f = *(const short8*)&Xlds[((16 + m_lane) * 25 + s * 4 + quad) * 8];
        short8 b0f = *(const short8*)&WoT[(size_t)(n0 + m_lane)      * KC + s * 32 + quad * 8];
        short8 b1f = *(const short8*)&WoT[(size_t)(n0 + 16 + m_lane) * KC + s * 32 + quad * 8];
        c00 = __builtin_amdgcn_mfma_f32_16x16x32_bf16(a0f, b0f, c00, 0, 0, 0);
        c01 = __builtin_amdgcn_mfma_f32_16x16x32_bf16(a0f, b1f, c01, 0, 0, 0);
        c10 = __builtin_amdgcn_mfma_f32_16x16x32_bf16(a1f, b0f, c10, 0, 0, 0);
        c11 = __builtin_amdgcn_mfma_f32_16x16x32_bf16(a1f, b1f, c11, 0, 0, 0);
    }

    #pragma unroll
    for (int r = 0; r < 4; r++) {
        int r0 = quad * 4 + r, r1 = r0 + 16;
        htile[r0 * H + n0 + m_lane]      = fmaxf(c00[r], 0.f);
        htile[r0 * H + n0 + 16 + m_lane] = fmaxf(c01[r], 0.f);
        htile[r1 * H + n0 + m_lane]      = fmaxf(c10[r], 0.f);
        htile[r1 * H + n0 + 16 + m_lane] = fmaxf(c11[r], 0.f);
    }
    __syncthreads();

    // segmented reduce over the 32-atom tile, one atomicAdd per (segment,col)
    if (tid < H) {
        int j = tid;
        float acc = 0.f;
        int cur = mlds[0];
        for (int r = 0; r < 32; r++) {
            int m = mlds[r];
            if (m != cur) {
                atomicAdd(&out[(size_t)cur * H + j], acc);
                acc = 0.f; cur = m;
            }
            acc += htile[r * H + j];
        }
        atomicAdd(&out[(size_t)cur * H + j], acc);
    }
}

// ---------------------------------------------------------------------------
// pool_div: out[m] /= count(m)  (counts via binary search on sorted mol_ids)
// ---------------------------------------------------------------------------
__global__ __launch_bounds__(128) void pool_div(
    const int* __restrict__ mol_ids, float* __restrict__ out, int n_atoms)
{
    int m = blockIdx.x;
    int j = threadIdx.x;

    int lo = 0, hi = n_atoms;
    while (lo < hi) { int mid = (lo + hi) >> 1; if (mol_ids[mid] < m) lo = mid + 1; else hi = mid; }
    int start = lo;
    hi = n_atoms;
    while (lo < hi) { int mid = (lo + hi) >> 1; if (mol_ids[mid] < m + 1) lo = mid + 1; else hi = mid; }
    int end = lo;

    out[(size_t)m * H + j] /= fmaxf((float)(end - start), 1.f);
}

// ---------------------------------------------------------------------------
extern "C" void kernel_launch(void* const* d_in, const int* in_sizes, int n_in,
                              void* d_out, int out_size, void* d_ws, size_t ws_size,
                              hipStream_t stream)
{
    const float* fatoms  = (const float*)d_in[0];
    const float* fbonds  = (const float*)d_in[1];
    const float* tree    = (const float*)d_in[2];
    const int*   agraph  = (const int*)d_in[3];
    const int*   bgraph  = (const int*)d_in[4];
    const int*   mol_ids = (const int*)d_in[5];
    const float* W_i = (const float*)d_in[7];
    const float* W_h = (const float*)d_in[8];
    const float* W_o = (const float*)d_in[9];
    const float* b_o = (const float*)d_in[10];
    float* out = (float*)d_out;

    // ws: mqA | mqB (u8 rows, 30.72 MB each) | scA | scB (u8 codes, 240 KB)
    //     | WT | WoT (48 KB each) | fbc (17.6 MB) | bgraphP (10.56 MB)
    //     | agraphP (4.8 MB)   ~95 MB
    uint2* mqA = (uint2*)d_ws;
    uint2* mqB = mqA + (size_t)N_MSG * 16;
    unsigned char* scA = (unsigned char*)(mqB + (size_t)N_MSG * 16);
    unsigned char* scB = scA + N_MSG;
    ushort* WT  = (ushort*)(scB + N_MSG);
    ushort* WoT = WT + (size_t)H * KC;
    ushort* fbc = WoT + (size_t)H * KC;
    int* bgP = (int*)(fbc + (size_t)N_BONDS * BOND_IN);
    int* agP = bgP + (size_t)N_BONDS * NB_PAD;

    int prep_total = PTe + out_size;
    prep<<<(prep_total + 255) / 256, 256, 0, stream>>>(
        fbonds, W_i, W_h, W_o, bgraph, agraph, fbc, WT, WoT, bgP, agP, out, out_size);

    qtree<<<N_MESS / 4, 256, 0, stream>>>(tree, (ushort*)mqA, (ushort*)mqB, scA, scB);

    binput0<<<N_BONDS / 32, 256, 0, stream>>>(fbc, WT,
        (uint4*)(mqA + (size_t)N_MESS * 16), scA + N_MESS);

    const uint2* tin = mqA; const unsigned char* sin = scA;
    uint2* tout = mqB; unsigned char* sout = scB;
    for (int r = 0; r < DEPTH - 1; r++) {
        mp_round<<<N_BONDS / 32, 256, 0, stream>>>(tin, sin, fbc, bgP, WT,
            (uint4*)(tout + (size_t)N_MESS * 16), sout + N_MESS);
        const uint2* t1 = tin; tin = tout; tout = (uint2*)t1;
        const unsigned char* t2 = sin; sin = sout; sout = (unsigned char*)t2;
    }
    // after 5 rounds the final message table is mqB (== tin)

    atom_mfma<<<N_ATOMS / 32, 256, 0, stream>>>(fatoms, tin, sin, agP, WoT, b_o,
                                                mol_ids, out);

    int n_mols = out_size / H;
    pool_div<<<n_mols, 128, 0, stream>>>(mol_ids, out, N_ATOMS);
}